// Round 4
// baseline (933.308 us; speedup 1.0000x reference)
//
#include <hip/hip_runtime.h>

typedef unsigned short u16;
typedef unsigned int u32;
typedef __attribute__((ext_vector_type(8))) __bf16 bf16x8;
typedef __attribute__((ext_vector_type(4))) float f32x4;

#define NB 65536     // batch rows
#define NEXP 8
#define MFMA16(a,b,c) __builtin_amdgcn_mfma_f32_16x16x32_bf16(a, b, c, 0, 0, 0)

union Frag { uint4 u; bf16x8 b; };

__device__ __forceinline__ u16 f2bf(float f){
  u32 u = __float_as_uint(f);
  u += 0x7fffu + ((u >> 16) & 1u);   // RNE
  return (u16)(u >> 16);
}
__device__ __forceinline__ float bf2f(u16 b){ return __uint_as_float(((u32)b) << 16); }

// mish(x) = x*tanh(softplus(x)) = x * w/(w+2),  w = u^2+2u, u = e^x
__device__ __forceinline__ float mish_f(float z){
  float u = __expf(fminf(z, 30.0f));
  float w = u * (u + 2.0f);
  return z * __fdividef(w, w + 2.0f);
}

// ---------------- prep: transpose f32 [E][R][C] -> bf16 [E][C][R] ----------------
__global__ void transpose_cvt(const float* __restrict__ in, u16* __restrict__ outp,
                              int R, int C){
  __shared__ float tl[32][33];
  int perE = (R/32)*(C/32);
  int e  = blockIdx.x / perE;
  int rem = blockIdx.x % perE;
  int tr = rem / (C/32);
  int tc = rem % (C/32);
  const float* src = in + (size_t)e * R * C;
  u16* dst = outp + (size_t)e * R * C;
  int j = threadIdx.x & 31, i0 = threadIdx.x >> 5;
  #pragma unroll
  for (int ii = 0; ii < 4; ++ii){
    int i = i0 + 8*ii;
    tl[i][j] = src[(size_t)(tr*32 + i)*C + tc*32 + j];
  }
  __syncthreads();
  #pragma unroll
  for (int ii = 0; ii < 4; ++ii){
    int i = i0 + 8*ii;
    dst[(size_t)(tc*32 + i)*R + tr*32 + j] = f2bf(tl[j][i]);
  }
}

// ---------------- prep: column sums of WT rows (len 256) ----------------
__global__ void csum_kernel(const u16* __restrict__ WT, float* __restrict__ cs){
  int idx = blockIdx.x * 256 + threadIdx.x;   // over E*256
  const u16* p = WT + (size_t)idx * 256;
  float s = 0.f;
  for (int h = 0; h < 256; ++h) s += bf2f(p[h]);
  cs[idx] = s;
}

// ---------------- gate: softmax(x @ Wg + bg) ----------------
__global__ void gate_kernel(const float* __restrict__ x, const float* __restrict__ Wg,
                            const float* __restrict__ bg, float* __restrict__ gate){
  __shared__ float wgs[128*8];
  __shared__ float bgs[8];
  int t = threadIdx.x;
  for (int i = t; i < 1024; i += 256) wgs[i] = Wg[i];
  if (t < 8) bgs[t] = bg[t];
  __syncthreads();
  int row = blockIdx.x * 256 + t;
  const float4* xr = (const float4*)(x + (size_t)row * 128);
  float acc[8];
  #pragma unroll
  for (int e = 0; e < 8; ++e) acc[e] = bgs[e];
  #pragma unroll
  for (int d4 = 0; d4 < 32; ++d4){
    float4 v = xr[d4];
    #pragma unroll
    for (int e = 0; e < 8; ++e){
      acc[e] += v.x*wgs[(4*d4+0)*8+e] + v.y*wgs[(4*d4+1)*8+e]
              + v.z*wgs[(4*d4+2)*8+e] + v.w*wgs[(4*d4+3)*8+e];
    }
  }
  float m = acc[0];
  #pragma unroll
  for (int e = 1; e < 8; ++e) m = fmaxf(m, acc[e]);
  float s = 0.f;
  #pragma unroll
  for (int e = 0; e < 8; ++e){ acc[e] = __expf(acc[e] - m); s += acc[e]; }
  float inv = 1.0f / s;
  #pragma unroll
  for (int e = 0; e < 8; ++e) gate[(size_t)row*8 + e] = acc[e] * inv;
}

// ---------------- LN stats: wave-reduce over 16 lanes, then fold coefficients ----------------
__device__ __forceinline__ void ln_stats(float (&s)[2][4], float (&q)[2][4],
                                         float (&sA)[2][4], float (&sB)[2][4]){
  #pragma unroll
  for (int m = 1; m < 16; m <<= 1)
    #pragma unroll
    for (int rf = 0; rf < 2; ++rf)
      #pragma unroll
      for (int i = 0; i < 4; ++i){
        s[rf][i] += __shfl_xor(s[rf][i], m, 64);
        q[rf][i] += __shfl_xor(q[rf][i], m, 64);
      }
  #pragma unroll
  for (int rf = 0; rf < 2; ++rf)
    #pragma unroll
    for (int i = 0; i < 4; ++i){
      float mu  = s[rf][i] * (1.0f/256.0f);
      float var = q[rf][i] * (1.0f/256.0f) - mu*mu;
      float rs  = rsqrtf(var + 1e-5f);
      sA[rf][i] = rs;
      sB[rf][i] = rs * mu;
    }
}

// ---------------- epilogues ----------------
template<bool STATS>
__device__ __forceinline__ void epi_mid(const f32x4& a0, const f32x4& a1, int ct,
    float cs, float bias, u16* hsh, int wrow, int g, int c,
    const float (&sA)[2][4], const float (&sB)[2][4],
    float (&so)[2][4], float (&qo)[2][4])
{
  #pragma unroll
  for (int rf = 0; rf < 2; ++rf){
    f32x4 acc = (rf == 0) ? a0 : a1;
    #pragma unroll
    for (int i = 0; i < 4; ++i){
      float z = sA[rf][i]*acc[i] - sB[rf][i]*cs + bias;
      float v = mish_f(z);
      if (STATS){ so[rf][i] += v; qo[rf][i] += v*v; }
      int r = wrow + 16*rf + 4*g + i;
      int elem = (r*256 + 16*ct + c) ^ (((r>>2)&3)<<4);
      *(__bf16*)&hsh[elem] = (__bf16)v;
    }
  }
}

__device__ __forceinline__ void epi_l1(const f32x4& a0, const f32x4& a1, int ct,
    float bias, u16* hsh, int wrow, int g, int c,
    float (&so)[2][4], float (&qo)[2][4])
{
  #pragma unroll
  for (int rf = 0; rf < 2; ++rf){
    f32x4 acc = (rf == 0) ? a0 : a1;
    #pragma unroll
    for (int i = 0; i < 4; ++i){
      float z = acc[i] + bias;
      float v = mish_f(z);
      so[rf][i] += v; qo[rf][i] += v*v;
      int r = wrow + 16*rf + 4*g + i;
      int elem = (r*256 + 16*ct + c) ^ (((r>>2)&3)<<4);
      *(__bf16*)&hsh[elem] = (__bf16)v;
    }
  }
}

// ---------------- mid layer (K=256, 256 cols), ping-pong weight prefetch ----------------
template<bool STATS>
__device__ __forceinline__ void mid_layer(
    const u16* __restrict__ w, const float* __restrict__ cse, const float* __restrict__ be,
    u16* hsh, int wrow, int g, int c,
    const float (&sA)[2][4], const float (&sB)[2][4],
    float (&so)[2][4], float (&qo)[2][4])
{
  Frag hA[2][8];
  #pragma unroll
  for (int rf = 0; rf < 2; ++rf)
    #pragma unroll
    for (int kk = 0; kk < 8; ++kk){
      int r = wrow + 16*rf + c;
      int elem = (r*256 + 32*kk + 8*g) ^ (((r>>2)&3)<<4);
      hA[rf][kk].u = *(const uint4*)&hsh[elem];
    }
  Frag bp0[8], bp1[8];
  {
    const u16* pb = w + c*256 + 8*g;
    #pragma unroll
    for (int kk = 0; kk < 8; ++kk) bp0[kk].u = *(const uint4*)(pb + 32*kk);
  }
  #pragma unroll 1
  for (int ct2 = 0; ct2 < 8; ++ct2){
    const int ctA = 2*ct2, ctB = 2*ct2 + 1;
    float csA = cse[16*ctA + c], biasA = be[16*ctA + c];
    float csB = cse[16*ctB + c], biasB = be[16*ctB + c];
    {  // prefetch B half (in flight during A's MFMAs + epilogue)
      const u16* pb = w + (16*ctB + c)*256 + 8*g;
      #pragma unroll
      for (int kk = 0; kk < 8; ++kk) bp1[kk].u = *(const uint4*)(pb + 32*kk);
    }
    f32x4 a0 = {0,0,0,0}, a1 = {0,0,0,0};
    #pragma unroll
    for (int kk = 0; kk < 8; ++kk){
      a0 = MFMA16(hA[0][kk].b, bp0[kk].b, a0);
      a1 = MFMA16(hA[1][kk].b, bp0[kk].b, a1);
    }
    if (ct2 < 7){  // prefetch next A half (in flight during epilogue A + B's MFMAs)
      const u16* pb = w + (16*(ctA+2) + c)*256 + 8*g;
      #pragma unroll
      for (int kk = 0; kk < 8; ++kk) bp0[kk].u = *(const uint4*)(pb + 32*kk);
    }
    epi_mid<STATS>(a0, a1, ctA, csA, biasA, hsh, wrow, g, c, sA, sB, so, qo);
    f32x4 a2 = {0,0,0,0}, a3 = {0,0,0,0};
    #pragma unroll
    for (int kk = 0; kk < 8; ++kk){
      a2 = MFMA16(hA[0][kk].b, bp1[kk].b, a2);
      a3 = MFMA16(hA[1][kk].b, bp1[kk].b, a3);
    }
    epi_mid<STATS>(a2, a3, ctB, csB, biasB, hsh, wrow, g, c, sA, sB, so, qo);
  }
}

// ---------------- main fused kernel ----------------
// NOTE (R4): L4's ct2 loop MUST be fully unrolled — with `#pragma unroll 1`
// oacc[rf][2*ct2][i] is a runtime-indexed register array, which the compiler
// is forced to place in scratch MEMORY (R2/R3: +250 MB spill traffic/dispatch,
// rocprof WRITE_SIZE 352 MB vs 32 MB of real output). Static indices keep oacc
// in the unified VGPR/AGPR file.
__global__ __launch_bounds__(256, 2)
void moe_main(const float* __restrict__ x, const float* __restrict__ gate,
              const u16* __restrict__ W1T, const u16* __restrict__ W2T,
              const u16* __restrict__ W3T, const u16* __restrict__ W4T,
              const float* __restrict__ b1, const float* __restrict__ b2,
              const float* __restrict__ b3, const float* __restrict__ b4,
              const float* __restrict__ cs2, const float* __restrict__ cs3,
              float* __restrict__ out)
{
  __shared__ u16 hsh[128*256];          // 64 KB, wave-private 32-row slices -> no barriers
  const int t = threadIdx.x;
  const int lane = t & 63;
  const int wid  = t >> 6;
  const int g = lane >> 4;              // k-group
  const int c = lane & 15;              // A-row / B-col / D-col
  const int wrow = wid * 32;
  const int rowblk = blockIdx.x * 128;

  float oacc[2][8][4];
  #pragma unroll
  for (int rf = 0; rf < 2; ++rf)
    #pragma unroll
    for (int ct = 0; ct < 8; ++ct)
      #pragma unroll
      for (int i = 0; i < 4; ++i) oacc[rf][ct][i] = 0.f;

  #pragma unroll 1
  for (int e = 0; e < NEXP; ++e){
    const u16* w1 = W1T + e*(256*128);
    const u16* w2 = W2T + e*(256*256);
    const u16* w3 = W3T + e*(256*256);
    const u16* w4 = W4T + e*(128*256);
    const float* b1e = b1 + e*256;
    const float* b2e = b2 + e*256;
    const float* b3e = b3 + e*256;
    const float* b4e = b4 + e*128;
    const float* c2e = cs2 + e*256;
    const float* c3e = cs3 + e*256;

    // x A-fragments (f32 global -> bf16 regs), K=128
    Frag xA[2][4];
    #pragma unroll
    for (int rf = 0; rf < 2; ++rf)
      #pragma unroll
      for (int kk = 0; kk < 4; ++kk){
        const float* p = x + (size_t)(rowblk + wrow + 16*rf + c)*128 + 32*kk + 8*g;
        float4 v0 = *(const float4*)p;
        float4 v1 = *(const float4*)(p + 4);
        Frag fr;
        fr.b[0] = (__bf16)v0.x; fr.b[1] = (__bf16)v0.y;
        fr.b[2] = (__bf16)v0.z; fr.b[3] = (__bf16)v0.w;
        fr.b[4] = (__bf16)v1.x; fr.b[5] = (__bf16)v1.y;
        fr.b[6] = (__bf16)v1.z; fr.b[7] = (__bf16)v1.w;
        xA[rf][kk] = fr;
      }

    // ---- Layer 1: [*,128]@[128,256], bias+mish, stats; ping-pong prefetch
    float s[2][4], q[2][4];
    #pragma unroll
    for (int rf = 0; rf < 2; ++rf)
      #pragma unroll
      for (int i = 0; i < 4; ++i){ s[rf][i] = 0.f; q[rf][i] = 0.f; }

    {
      Frag bp0[4], bp1[4];
      {
        const u16* pb = w1 + c*128 + 8*g;
        #pragma unroll
        for (int kk = 0; kk < 4; ++kk) bp0[kk].u = *(const uint4*)(pb + 32*kk);
      }
      #pragma unroll 1
      for (int ct2 = 0; ct2 < 8; ++ct2){
        const int ctA = 2*ct2, ctB = 2*ct2 + 1;
        float biasA = b1e[16*ctA + c], biasB = b1e[16*ctB + c];
        {
          const u16* pb = w1 + (16*ctB + c)*128 + 8*g;
          #pragma unroll
          for (int kk = 0; kk < 4; ++kk) bp1[kk].u = *(const uint4*)(pb + 32*kk);
        }
        f32x4 a0 = {0,0,0,0}, a1 = {0,0,0,0};
        #pragma unroll
        for (int kk = 0; kk < 4; ++kk){
          a0 = MFMA16(xA[0][kk].b, bp0[kk].b, a0);
          a1 = MFMA16(xA[1][kk].b, bp0[kk].b, a1);
        }
        if (ct2 < 7){
          const u16* pb = w1 + (16*(ctA+2) + c)*128 + 8*g;
          #pragma unroll
          for (int kk = 0; kk < 4; ++kk) bp0[kk].u = *(const uint4*)(pb + 32*kk);
        }
        epi_l1(a0, a1, ctA, biasA, hsh, wrow, g, c, s, q);
        f32x4 a2 = {0,0,0,0}, a3 = {0,0,0,0};
        #pragma unroll
        for (int kk = 0; kk < 4; ++kk){
          a2 = MFMA16(xA[0][kk].b, bp1[kk].b, a2);
          a3 = MFMA16(xA[1][kk].b, bp1[kk].b, a3);
        }
        epi_l1(a2, a3, ctB, biasB, hsh, wrow, g, c, s, q);
      }
    }
    float sc[2][4], sh[2][4];
    ln_stats(s, q, sc, sh);

    // ---- Layer 2 (LN folded) with stats
    #pragma unroll
    for (int rf = 0; rf < 2; ++rf)
      #pragma unroll
      for (int i = 0; i < 4; ++i){ s[rf][i] = 0.f; q[rf][i] = 0.f; }
    mid_layer<true>(w2, c2e, b2e, hsh, wrow, g, c, sc, sh, s, q);
    ln_stats(s, q, sc, sh);

    // ---- Layer 3 (LN folded), no stats
    mid_layer<false>(w3, c3e, b3e, hsh, wrow, g, c, sc, sh, s, q);

    // ---- Layer 4: [*,256]@[256,128] + b4, gate-weighted accumulate
    // FULLY UNROLLED so oacc indices are compile-time (see NOTE above).
    {
      Frag hA[2][8];
      #pragma unroll
      for (int rf = 0; rf < 2; ++rf)
        #pragma unroll
        for (int kk = 0; kk < 8; ++kk){
          int r = wrow + 16*rf + c;
          int elem = (r*256 + 32*kk + 8*g) ^ (((r>>2)&3)<<4);
          hA[rf][kk].u = *(const uint4*)&hsh[elem];
        }
      float gv[2][4];
      #pragma unroll
      for (int rf = 0; rf < 2; ++rf)
        #pragma unroll
        for (int i = 0; i < 4; ++i)
          gv[rf][i] = gate[(size_t)(rowblk + wrow + 16*rf + 4*g + i)*NEXP + e];

      #pragma unroll
      for (int ct = 0; ct < 8; ++ct){
        f32x4 a0 = {0,0,0,0}, a1 = {0,0,0,0};
        const u16* pb = w4 + (16*ct + c)*256 + 8*g;
        #pragma unroll
        for (int kk = 0; kk < 8; ++kk){
          Frag bf; bf.u = *(const uint4*)(pb + 32*kk);
          a0 = MFMA16(hA[0][kk].b, bf.b, a0);
          a1 = MFMA16(hA[1][kk].b, bf.b, a1);
        }
        float bias = b4e[16*ct + c];
        #pragma unroll
        for (int rf = 0; rf < 2; ++rf){
          f32x4 acc = (rf == 0) ? a0 : a1;
          #pragma unroll
          for (int i = 0; i < 4; ++i)
            oacc[rf][ct][i] += gv[rf][i] * (acc[i] + bias);
        }
      }
    }
  }

  // ---- store output [B,128] f32
  #pragma unroll
  for (int rf = 0; rf < 2; ++rf)
    #pragma unroll
    for (int ct = 0; ct < 8; ++ct)
      #pragma unroll
      for (int i = 0; i < 4; ++i)
        out[(size_t)(rowblk + wrow + 16*rf + 4*g + i)*128 + 16*ct + c] = oacc[rf][ct][i];
}

extern "C" void kernel_launch(void* const* d_in, const int* in_sizes, int n_in,
                              void* d_out, int out_size, void* d_ws, size_t ws_size,
                              hipStream_t stream)
{
  const float* x  = (const float*)d_in[0];
  const float* Wg = (const float*)d_in[1];
  const float* bg = (const float*)d_in[2];
  const float* W1 = (const float*)d_in[3];
  const float* b1 = (const float*)d_in[4];
  const float* W2 = (const float*)d_in[5];
  const float* b2 = (const float*)d_in[6];
  const float* W3 = (const float*)d_in[7];
  const float* b3 = (const float*)d_in[8];
  const float* W4 = (const float*)d_in[9];
  const float* b4 = (const float*)d_in[10];
  float* out = (float*)d_out;

  char* ws = (char*)d_ws;
  size_t off = 0;
  float* gate = (float*)(ws + off); off += (size_t)NB * 8 * 4;        // 2 MB
  u16* W1T = (u16*)(ws + off); off += (size_t)8 * 256 * 128 * 2;      // 512 KB
  u16* W2T = (u16*)(ws + off); off += (size_t)8 * 256 * 256 * 2;      // 1 MB
  u16* W3T = (u16*)(ws + off); off += (size_t)8 * 256 * 256 * 2;      // 1 MB
  u16* W4T = (u16*)(ws + off); off += (size_t)8 * 128 * 256 * 2;      // 512 KB
  float* c2 = (float*)(ws + off); off += 8 * 256 * 4;                 // 8 KB
  float* c3 = (float*)(ws + off); off += 8 * 256 * 4;                 // 8 KB

  // weight prep: f32 [E][R][C] -> bf16 [E][C][R]
  transpose_cvt<<<8*(128/32)*(256/32), 256, 0, stream>>>(W1, W1T, 128, 256);
  transpose_cvt<<<8*(256/32)*(256/32), 256, 0, stream>>>(W2, W2T, 256, 256);
  transpose_cvt<<<8*(256/32)*(256/32), 256, 0, stream>>>(W3, W3T, 256, 256);
  transpose_cvt<<<8*(256/32)*(128/32), 256, 0, stream>>>(W4, W4T, 256, 128);
  csum_kernel<<<8, 256, 0, stream>>>(W2T, c2);
  csum_kernel<<<8, 256, 0, stream>>>(W3T, c3);
  gate_kernel<<<NB/256, 256, 0, stream>>>(x, Wg, bg, gate);

  moe_main<<<NB/128, 256, 0, stream>>>(x, gate, W1T, W2T, W3T, W4T,
                                       b1, b2, b3, b4, c2, c3, out);
}

// Round 7
// 777.859 us; speedup vs baseline: 1.1998x; 1.1998x over previous
//
#include <hip/hip_runtime.h>

typedef unsigned short u16;
typedef unsigned int u32;
typedef __attribute__((ext_vector_type(8))) __bf16 bf16x8;
typedef __attribute__((ext_vector_type(4))) float f32x4;
typedef uint4 __attribute__((may_alias)) uint4a;   // LDS vector loads alias u16 stores

#define NB 65536     // batch rows
#define NEXP 8
#define MFMA16(a,b,c) __builtin_amdgcn_mfma_f32_16x16x32_bf16(a, b, c, 0, 0, 0)

union Frag { uint4 u; bf16x8 b; };

__device__ __forceinline__ u16 f2bf(float f){
  u32 u = __float_as_uint(f);
  u += 0x7fffu + ((u >> 16) & 1u);   // RNE
  return (u16)(u >> 16);
}
__device__ __forceinline__ float bf2f(u16 b){ return __uint_as_float(((u32)b) << 16); }

// mish(x) = x*tanh(softplus(x)) = x * w/(w+2),  w = u^2+2u, u = e^x
__device__ __forceinline__ float mish_f(float z){
  float u = __expf(fminf(z, 30.0f));
  float w = u * (u + 2.0f);
  return z * __fdividef(w, w + 2.0f);
}

// ---- Register staging (replaces global_load_lds; R5/R6 raced under graph
// replay — divergent-LDS-dest DMA is the one unverified primitive, so it's
// gone). Thread t loads bytes [t*16, t*16+16) (+r*4096) of the tile into
// VGPRs at the TOP of an iteration (latency hides under MFMA+epilogue) and
// ds_writes them to the XOR-SWIZZLED dest at the BOTTOM, before the barrier.
// ds_write -> s_barrier(lgkmcnt 0) -> ds_read is bulletproof ordering.
template<int BYTES>
__device__ __forceinline__ void stage_load(const u16* gsrc, int tid, uint4* tmp){
  #pragma unroll
  for (int r = 0; r < BYTES/4096; ++r)
    tmp[r] = *(const uint4*)((const char*)gsrc + tid*16 + r*4096);
}
template<int BYTES, int ROWSHIFT>
__device__ __forceinline__ void stage_write(u16* ldst, int tid, const uint4* tmp){
  #pragma unroll
  for (int r = 0; r < BYTES/4096; ++r){
    u32 p = (u32)(tid*16 + r*4096);                 // linear byte offset in tile
    u32 d = p ^ (((p >> ROWSHIFT) & 7u) << 4);      // swizzle dest, stays in row
    *(uint4*)((char*)ldst + d) = tmp[r];
  }
}

// B-fragment read: lane (c,g), k-chunk kk. Linear addr ^ ((row&7)<<4).
template<int ROWSHIFT>
__device__ __forceinline__ Frag read_bfrag(const u16* tile, int c, int kk, int g){
  u32 a = ((u32)c << ROWSHIFT) + (u32)kk*64u + (u32)g*16u;
  a ^= ((u32)(c & 7) << 4);
  Frag f; f.u = *(const uint4a*)((const char*)tile + a);
  return f;
}

// ---------------- prep: transpose f32 [E][R][C] -> bf16 [E][C][R] ----------------
__global__ void transpose_cvt(const float* __restrict__ in, u16* __restrict__ outp,
                              int R, int C){
  __shared__ float tl[32][33];
  int perE = (R/32)*(C/32);
  int e  = blockIdx.x / perE;
  int rem = blockIdx.x % perE;
  int tr = rem / (C/32);
  int tc = rem % (C/32);
  const float* src = in + (size_t)e * R * C;
  u16* dst = outp + (size_t)e * R * C;
  int j = threadIdx.x & 31, i0 = threadIdx.x >> 5;
  #pragma unroll
  for (int ii = 0; ii < 4; ++ii){
    int i = i0 + 8*ii;
    tl[i][j] = src[(size_t)(tr*32 + i)*C + tc*32 + j];
  }
  __syncthreads();
  #pragma unroll
  for (int ii = 0; ii < 4; ++ii){
    int i = i0 + 8*ii;
    dst[(size_t)(tc*32 + i)*R + tr*32 + j] = f2bf(tl[j][i]);
  }
}

// ---------------- prep: column sums of WT rows (len 256) ----------------
__global__ void csum_kernel(const u16* __restrict__ WT, float* __restrict__ cs){
  int idx = blockIdx.x * 256 + threadIdx.x;   // over E*256
  const u16* p = WT + (size_t)idx * 256;
  float s = 0.f;
  for (int h = 0; h < 256; ++h) s += bf2f(p[h]);
  cs[idx] = s;
}

// ---------------- gate: softmax(x @ Wg + bg), TRANSPOSED output [E][B] ----------------
__global__ void gate_kernel(const float* __restrict__ x, const float* __restrict__ Wg,
                            const float* __restrict__ bg, float* __restrict__ gate){
  __shared__ float wgs[128*8];
  __shared__ float bgs[8];
  int t = threadIdx.x;
  for (int i = t; i < 1024; i += 256) wgs[i] = Wg[i];
  if (t < 8) bgs[t] = bg[t];
  __syncthreads();
  int row = blockIdx.x * 256 + t;
  const float4* xr = (const float4*)(x + (size_t)row * 128);
  float acc[8];
  #pragma unroll
  for (int e = 0; e < 8; ++e) acc[e] = bgs[e];
  #pragma unroll
  for (int d4 = 0; d4 < 32; ++d4){
    float4 v = xr[d4];
    #pragma unroll
    for (int e = 0; e < 8; ++e){
      acc[e] += v.x*wgs[(4*d4+0)*8+e] + v.y*wgs[(4*d4+1)*8+e]
              + v.z*wgs[(4*d4+2)*8+e] + v.w*wgs[(4*d4+3)*8+e];
    }
  }
  float m = acc[0];
  #pragma unroll
  for (int e = 1; e < 8; ++e) m = fmaxf(m, acc[e]);
  float s = 0.f;
  #pragma unroll
  for (int e = 0; e < 8; ++e){ acc[e] = __expf(acc[e] - m); s += acc[e]; }
  float inv = 1.0f / s;
  #pragma unroll
  for (int e = 0; e < 8; ++e) gate[(size_t)e*NB + row] = acc[e] * inv;
}

// ---------------- LN stats: wave-reduce over 16 lanes, then fold coefficients ----------------
__device__ __forceinline__ void ln_stats(float (&s)[2][4], float (&q)[2][4],
                                         float (&sA)[2][4], float (&sB)[2][4]){
  #pragma unroll
  for (int m = 1; m < 16; m <<= 1)
    #pragma unroll
    for (int rf = 0; rf < 2; ++rf)
      #pragma unroll
      for (int i = 0; i < 4; ++i){
        s[rf][i] += __shfl_xor(s[rf][i], m, 64);
        q[rf][i] += __shfl_xor(q[rf][i], m, 64);
      }
  #pragma unroll
  for (int rf = 0; rf < 2; ++rf)
    #pragma unroll
    for (int i = 0; i < 4; ++i){
      float mu  = s[rf][i] * (1.0f/256.0f);
      float var = q[rf][i] * (1.0f/256.0f) - mu*mu;
      float rs  = rsqrtf(var + 1e-5f);
      sA[rf][i] = rs;
      sB[rf][i] = rs * mu;
    }
}

// ---------------- epilogues ----------------
template<bool STATS>
__device__ __forceinline__ void epi_mid(const f32x4& a0, const f32x4& a1, int ct,
    float cs, float bias, u16* hsh, int wrow, int g, int c,
    const float (&sA)[2][4], const float (&sB)[2][4],
    float (&so)[2][4], float (&qo)[2][4])
{
  #pragma unroll
  for (int rf = 0; rf < 2; ++rf){
    f32x4 acc = (rf == 0) ? a0 : a1;
    #pragma unroll
    for (int i = 0; i < 4; ++i){
      float z = sA[rf][i]*acc[i] - sB[rf][i]*cs + bias;
      float v = mish_f(z);
      if (STATS){ so[rf][i] += v; qo[rf][i] += v*v; }
      int r = wrow + 16*rf + 4*g + i;
      int elem = (r*256 + 16*ct + c) ^ (((r>>2)&3)<<4);
      hsh[elem] = f2bf(v);
    }
  }
}

__device__ __forceinline__ void epi_l1(const f32x4& a0, const f32x4& a1, int ct,
    float bias, u16* hsh, int wrow, int g, int c,
    float (&so)[2][4], float (&qo)[2][4])
{
  #pragma unroll
  for (int rf = 0; rf < 2; ++rf){
    f32x4 acc = (rf == 0) ? a0 : a1;
    #pragma unroll
    for (int i = 0; i < 4; ++i){
      float z = acc[i] + bias;
      float v = mish_f(z);
      so[rf][i] += v; qo[rf][i] += v*v;
      int r = wrow + 16*rf + 4*g + i;
      int elem = (r*256 + 16*ct + c) ^ (((r>>2)&3)<<4);
      hsh[elem] = f2bf(v);
    }
  }
}

// ---------------- mid layer (K=256, 256 cols): weights double-buffered in LDS ----------------
template<bool STATS>
__device__ __forceinline__ void mid_layer(
    const u16* __restrict__ w, const float* __restrict__ cse, const float* __restrict__ be,
    u16* hsh, u16* wbuf, int tid, int wrow, int g, int c,
    const float (&sA)[2][4], const float (&sB)[2][4],
    float (&so)[2][4], float (&qo)[2][4])
{
  Frag hA[2][8];
  #pragma unroll
  for (int rf = 0; rf < 2; ++rf)
    #pragma unroll
    for (int kk = 0; kk < 8; ++kk){
      int r = wrow + 16*rf + c;
      int elem = (r*256 + 32*kk + 8*g) ^ (((r>>2)&3)<<4);
      hA[rf][kk].u = *(const uint4a*)&hsh[elem];
    }
  {
    uint4 st[2];
    stage_load<8192>(w, tid, st);
    stage_write<8192,9>(wbuf, tid, st);
  }
  __syncthreads();
  #pragma unroll 1
  for (int ct = 0; ct < 16; ++ct){
    uint4 st[2];
    if (ct < 15) stage_load<8192>(w + (ct+1)*16*256, tid, st);   // issue early
    const u16* tb = wbuf + (ct&1)*4096;
    float cs = cse[16*ct + c], bias = be[16*ct + c];
    f32x4 a0 = {0,0,0,0}, a1 = {0,0,0,0};
    #pragma unroll
    for (int kk = 0; kk < 8; ++kk){
      Frag bf = read_bfrag<9>(tb, c, kk, g);
      a0 = MFMA16(hA[0][kk].b, bf.b, a0);
      a1 = MFMA16(hA[1][kk].b, bf.b, a1);
    }
    epi_mid<STATS>(a0, a1, ct, cs, bias, hsh, wrow, g, c, sA, sB, so, qo);
    if (ct < 15) stage_write<8192,9>(wbuf + ((ct+1)&1)*4096, tid, st);  // write late
    __syncthreads();
  }
}

// ---------------- main fused kernel ----------------
// LDS: 64 KB h-buffer (wave-private rows) + 16 KB weight double-buffer = 80 KB
// -> 2 blocks/CU. Weights staged once per block (shared by 4 waves) via
// REGISTER staging (load-early/ds_write-late): standard-primitive ordering,
// no global_load_lds (R5/R6's replay race source).
__global__ __launch_bounds__(256, 2)
void moe_main(const float* __restrict__ x, const float* __restrict__ gate,
              const u16* __restrict__ W1T, const u16* __restrict__ W2T,
              const u16* __restrict__ W3T, const u16* __restrict__ W4T,
              const float* __restrict__ b1, const float* __restrict__ b2,
              const float* __restrict__ b3, const float* __restrict__ b4,
              const float* __restrict__ cs2, const float* __restrict__ cs3,
              float* __restrict__ out)
{
  __shared__ u16 hsh[128*256];          // 64 KB
  __shared__ u16 wbuf[2*4096];          // 16 KB, two 8 KB tile slots
  const int t = threadIdx.x;
  const int lane = t & 63;
  const int wid  = t >> 6;
  const int g = lane >> 4;              // k-group
  const int c = lane & 15;              // A-row / B-col / D-col
  const int wrow = wid * 32;
  const int rowblk = blockIdx.x * 128;

  // x A-fragments: expert-invariant, load ONCE (f32 global -> bf16 regs)
  Frag xA[2][4];
  #pragma unroll
  for (int rf = 0; rf < 2; ++rf)
    #pragma unroll
    for (int kk = 0; kk < 4; ++kk){
      const float* p = x + (size_t)(rowblk + wrow + 16*rf + c)*128 + 32*kk + 8*g;
      float4 v0 = *(const float4*)p;
      float4 v1 = *(const float4*)(p + 4);
      Frag fr;
      fr.b[0] = (__bf16)v0.x; fr.b[1] = (__bf16)v0.y;
      fr.b[2] = (__bf16)v0.z; fr.b[3] = (__bf16)v0.w;
      fr.b[4] = (__bf16)v1.x; fr.b[5] = (__bf16)v1.y;
      fr.b[6] = (__bf16)v1.z; fr.b[7] = (__bf16)v1.w;
      xA[rf][kk] = fr;
    }

  float oacc[2][8][4];
  #pragma unroll
  for (int rf = 0; rf < 2; ++rf)
    #pragma unroll
    for (int ct = 0; ct < 8; ++ct)
      #pragma unroll
      for (int i = 0; i < 4; ++i) oacc[rf][ct][i] = 0.f;

  #pragma unroll 1
  for (int e = 0; e < NEXP; ++e){
    const u16* w1 = W1T + e*(256*128);
    const u16* w2 = W2T + e*(256*256);
    const u16* w3 = W3T + e*(256*256);
    const u16* w4 = W4T + e*(128*256);
    const float* b1e = b1 + e*256;
    const float* b2e = b2 + e*256;
    const float* b3e = b3 + e*256;
    const float* b4e = b4 + e*128;
    const float* c2e = cs2 + e*256;
    const float* c3e = cs3 + e*256;

    // ---- Layer 1: [*,128]@[128,256], bias+mish, stats
    float s[2][4], q[2][4];
    #pragma unroll
    for (int rf = 0; rf < 2; ++rf)
      #pragma unroll
      for (int i = 0; i < 4; ++i){ s[rf][i] = 0.f; q[rf][i] = 0.f; }

    {
      uint4 st[1];
      stage_load<4096>(w1, t, st);
      stage_write<4096,8>(wbuf, t, st);
    }
    __syncthreads();
    #pragma unroll 1
    for (int ct = 0; ct < 16; ++ct){
      uint4 st[1];
      if (ct < 15) stage_load<4096>(w1 + (ct+1)*16*128, t, st);
      const u16* tb = wbuf + (ct&1)*4096;
      float bias = b1e[16*ct + c];
      f32x4 a0 = {0,0,0,0}, a1 = {0,0,0,0};
      #pragma unroll
      for (int kk = 0; kk < 4; ++kk){
        Frag bf = read_bfrag<8>(tb, c, kk, g);
        a0 = MFMA16(xA[0][kk].b, bf.b, a0);
        a1 = MFMA16(xA[1][kk].b, bf.b, a1);
      }
      epi_l1(a0, a1, ct, bias, hsh, wrow, g, c, s, q);
      if (ct < 15) stage_write<4096,8>(wbuf + ((ct+1)&1)*4096, t, st);
      __syncthreads();
    }
    float sc[2][4], sh[2][4];
    ln_stats(s, q, sc, sh);

    // ---- Layer 2 (LN folded) with stats
    #pragma unroll
    for (int rf = 0; rf < 2; ++rf)
      #pragma unroll
      for (int i = 0; i < 4; ++i){ s[rf][i] = 0.f; q[rf][i] = 0.f; }
    mid_layer<true>(w2, c2e, b2e, hsh, wbuf, t, wrow, g, c, sc, sh, s, q);
    ln_stats(s, q, sc, sh);

    // ---- Layer 3 (LN folded), no stats
    mid_layer<false>(w3, c3e, b3e, hsh, wbuf, t, wrow, g, c, sc, sh, s, q);

    // ---- Layer 4: [*,256]@[256,128] + b4, gate-weighted accumulate
    {
      Frag hA[2][8];
      #pragma unroll
      for (int rf = 0; rf < 2; ++rf)
        #pragma unroll
        for (int kk = 0; kk < 8; ++kk){
          int r = wrow + 16*rf + c;
          int elem = (r*256 + 32*kk + 8*g) ^ (((r>>2)&3)<<4);
          hA[rf][kk].u = *(const uint4a*)&hsh[elem];
        }
      float gv[2][4];
      #pragma unroll
      for (int rf = 0; rf < 2; ++rf)
        #pragma unroll
        for (int i = 0; i < 4; ++i)
          gv[rf][i] = gate[(size_t)e*NB + rowblk + wrow + 16*rf + 4*g + i];

      {
        uint4 st[2];
        stage_load<8192>(w4, t, st);
        stage_write<8192,9>(wbuf, t, st);
      }
      __syncthreads();
      #pragma unroll
      for (int ct = 0; ct < 8; ++ct){
        uint4 st[2];
        if (ct < 7) stage_load<8192>(w4 + (ct+1)*16*256, t, st);
        const u16* tb = wbuf + (ct&1)*4096;
        float bias = b4e[16*ct + c];
        f32x4 a0 = {0,0,0,0}, a1 = {0,0,0,0};
        #pragma unroll
        for (int kk = 0; kk < 8; ++kk){
          Frag bf = read_bfrag<9>(tb, c, kk, g);
          a0 = MFMA16(hA[0][kk].b, bf.b, a0);
          a1 = MFMA16(hA[1][kk].b, bf.b, a1);
        }
        #pragma unroll
        for (int rf = 0; rf < 2; ++rf){
          f32x4 acc = (rf == 0) ? a0 : a1;
          #pragma unroll
          for (int i = 0; i < 4; ++i)
            oacc[rf][ct][i] += gv[rf][i] * (acc[i] + bias);
        }
        if (ct < 7) stage_write<8192,9>(wbuf + ((ct+1)&1)*4096, t, st);
        __syncthreads();
      }
    }
  }

  // ---- store output [B,128] f32
  #pragma unroll
  for (int rf = 0; rf < 2; ++rf)
    #pragma unroll
    for (int ct = 0; ct < 8; ++ct)
      #pragma unroll
      for (int i = 0; i < 4; ++i)
        out[(size_t)(rowblk + wrow + 16*rf + 4*g + i)*128 + 16*ct + c] = oacc[rf][ct][i];
}

extern "C" void kernel_launch(void* const* d_in, const int* in_sizes, int n_in,
                              void* d_out, int out_size, void* d_ws, size_t ws_size,
                              hipStream_t stream)
{
  const float* x  = (const float*)d_in[0];
  const float* Wg = (const float*)d_in[1];
  const float* bg = (const float*)d_in[2];
  const float* W1 = (const float*)d_in[3];
  const float* b1 = (const float*)d_in[4];
  const float* W2 = (const float*)d_in[5];
  const float* b2 = (const float*)d_in[6];
  const float* W3 = (const float*)d_in[7];
  const float* b3 = (const float*)d_in[8];
  const float* W4 = (const float*)d_in[9];
  const float* b4 = (const float*)d_in[10];
  float* out = (float*)d_out;

  char* ws = (char*)d_ws;
  size_t off = 0;
  float* gate = (float*)(ws + off); off += (size_t)NB * 8 * 4;        // 2 MB, [E][B]
  u16* W1T = (u16*)(ws + off); off += (size_t)8 * 256 * 128 * 2;      // 512 KB
  u16* W2T = (u16*)(ws + off); off += (size_t)8 * 256 * 256 * 2;      // 1 MB
  u16* W3T = (u16*)(ws + off); off += (size_t)8 * 256 * 256 * 2;      // 1 MB
  u16* W4T = (u16*)(ws + off); off += (size_t)8 * 128 * 256 * 2;      // 512 KB
  float* c2 = (float*)(ws + off); off += 8 * 256 * 4;                 // 8 KB
  float* c3 = (float*)(ws + off); off += 8 * 256 * 4;                 // 8 KB

  // weight prep: f32 [E][R][C] -> bf16 [E][C][R]
  transpose_cvt<<<8*(128/32)*(256/32), 256, 0, stream>>>(W1, W1T, 128, 256);
  transpose_cvt<<<8*(256/32)*(256/32), 256, 0, stream>>>(W2, W2T, 256, 256);
  transpose_cvt<<<8*(256/32)*(128/32), 256, 0, stream>>>(W4, W4T, 256, 128);
  transpose_cvt<<<8*(256/32)*(256/32), 256, 0, stream>>>(W3, W3T, 256, 256);
  csum_kernel<<<8, 256, 0, stream>>>(W2T, c2);
  csum_kernel<<<8, 256, 0, stream>>>(W3T, c3);
  gate_kernel<<<NB/256, 256, 0, stream>>>(x, Wg, bg, gate);

  moe_main<<<NB/128, 256, 0, stream>>>(x, gate, W1T, W2T, W3T, W4T,
                                       b1, b2, b3, b4, c2, c3, out);
}

// Round 8
// 649.931 us; speedup vs baseline: 1.4360x; 1.1968x over previous
//
#include <hip/hip_runtime.h>

typedef unsigned short u16;
typedef unsigned int u32;
typedef __attribute__((ext_vector_type(8))) __bf16 bf16x8;
typedef __attribute__((ext_vector_type(4))) float f32x4;
typedef uint4 __attribute__((may_alias)) uint4a;   // LDS vector ops alias u16 stores
typedef uint2 __attribute__((may_alias)) uint2a;

#define NB 65536     // batch rows
#define NEXP 8
#define MFMA16(a,b,c) __builtin_amdgcn_mfma_f32_16x16x32_bf16(a, b, c, 0, 0, 0)

union Frag  { uint4 u; bf16x8 b; };
union Pack4 { __bf16 h[4]; uint2 u2; };

__device__ __forceinline__ u16 f2bf(float f){
  u32 u = __float_as_uint(f);
  u += 0x7fffu + ((u >> 16) & 1u);   // RNE
  return (u16)(u >> 16);
}
__device__ __forceinline__ float bf2f(u16 b){ return __uint_as_float(((u32)b) << 16); }

// mish(x) = x*tanh(softplus(x)) = x * w/(w+2),  w = u^2+2u, u = e^x
__device__ __forceinline__ float mish_f(float z){
  float u = __expf(fminf(z, 30.0f));
  float w = u * (u + 2.0f);
  return z * __fdividef(w, w + 2.0f);
}

// hsh (h-buffer) swizzled element index. byte = r*512 + col*2, XOR ((r&7)<<4)
// -> 8 consecutive rows hit 8 distinct 16B bank-quads (2-way max = free).
// R7's ((r>>2)&3)<<4 spread 16 rows over only 4 quads -> 4-way conflicts
// (SQ_LDS_BANK_CONFLICT 34.6M). All hsh accesses are >=4-elem aligned and
// stay within one 8-elem granule, so the XOR is uniform per vector op.
__device__ __forceinline__ u32 hidx(int r, int col){
  return (u32)((r*256 + col) ^ ((r & 7) << 3));
}

// ---- Register staging of weight tiles (R7-verified path): load early into
// VGPRs, ds_write swizzled late, then barrier. 512 threads/block.
__device__ __forceinline__ void stage_load16(const u16* gsrc, int tid, uint4* t4){
  *t4 = *(const uint4*)((const char*)gsrc + tid*16);          // 8 KB tile
}
template<int ROWSHIFT>
__device__ __forceinline__ void stage_write16(u16* ldst, int tid, const uint4* t4){
  u32 p = (u32)tid*16u;
  u32 d = p ^ (((p >> ROWSHIFT) & 7u) << 4);
  *(uint4a*)((char*)ldst + d) = *t4;
}
__device__ __forceinline__ void stage_load8(const u16* gsrc, int tid, uint2* t2){
  *t2 = *(const uint2*)((const char*)gsrc + tid*8);           // 4 KB tile
}
template<int ROWSHIFT>
__device__ __forceinline__ void stage_write8(u16* ldst, int tid, const uint2* t2){
  u32 p = (u32)tid*8u;
  u32 d = p ^ (((p >> ROWSHIFT) & 7u) << 4);
  *(uint2a*)((char*)ldst + d) = *t2;
}

// Weight A-fragment read: lane (c,g) reads row(out_col)=c, k=32kk+8g..+7.
template<int ROWSHIFT>
__device__ __forceinline__ Frag read_wfrag(const u16* tile, int c, int kk, int g){
  u32 a = ((u32)c << ROWSHIFT) + (u32)kk*64u + (u32)g*16u;
  a ^= ((u32)(c & 7) << 4);
  Frag f; f.u = *(const uint4a*)((const char*)tile + a);
  return f;
}

// ---------------- prep: transpose f32 [E][R][C] -> bf16 [E][C][R] ----------------
__global__ void transpose_cvt(const float* __restrict__ in, u16* __restrict__ outp,
                              int R, int C){
  __shared__ float tl[32][33];
  int perE = (R/32)*(C/32);
  int e  = blockIdx.x / perE;
  int rem = blockIdx.x % perE;
  int tr = rem / (C/32);
  int tc = rem % (C/32);
  const float* src = in + (size_t)e * R * C;
  u16* dst = outp + (size_t)e * R * C;
  int j = threadIdx.x & 31, i0 = threadIdx.x >> 5;
  #pragma unroll
  for (int ii = 0; ii < 4; ++ii){
    int i = i0 + 8*ii;
    tl[i][j] = src[(size_t)(tr*32 + i)*C + tc*32 + j];
  }
  __syncthreads();
  #pragma unroll
  for (int ii = 0; ii < 4; ++ii){
    int i = i0 + 8*ii;
    dst[(size_t)(tc*32 + i)*R + tr*32 + j] = f2bf(tl[j][i]);
  }
}

// ---------------- prep: column sums of WT rows (len 256) ----------------
__global__ void csum_kernel(const u16* __restrict__ WT, float* __restrict__ cs){
  int idx = blockIdx.x * 256 + threadIdx.x;   // over E*256
  const u16* p = WT + (size_t)idx * 256;
  float s = 0.f;
  for (int h = 0; h < 256; ++h) s += bf2f(p[h]);
  cs[idx] = s;
}

// ---------------- gate: softmax(x @ Wg + bg), TRANSPOSED output [E][B] ----------------
__global__ void gate_kernel(const float* __restrict__ x, const float* __restrict__ Wg,
                            const float* __restrict__ bg, float* __restrict__ gate){
  __shared__ float wgs[128*8];
  __shared__ float bgs[8];
  int t = threadIdx.x;
  for (int i = t; i < 1024; i += 256) wgs[i] = Wg[i];
  if (t < 8) bgs[t] = bg[t];
  __syncthreads();
  int row = blockIdx.x * 256 + t;
  const float4* xr = (const float4*)(x + (size_t)row * 128);
  float acc[8];
  #pragma unroll
  for (int e = 0; e < 8; ++e) acc[e] = bgs[e];
  #pragma unroll
  for (int d4 = 0; d4 < 32; ++d4){
    float4 v = xr[d4];
    #pragma unroll
    for (int e = 0; e < 8; ++e){
      acc[e] += v.x*wgs[(4*d4+0)*8+e] + v.y*wgs[(4*d4+1)*8+e]
              + v.z*wgs[(4*d4+2)*8+e] + v.w*wgs[(4*d4+3)*8+e];
    }
  }
  float m = acc[0];
  #pragma unroll
  for (int e = 1; e < 8; ++e) m = fmaxf(m, acc[e]);
  float s = 0.f;
  #pragma unroll
  for (int e = 0; e < 8; ++e){ acc[e] = __expf(acc[e] - m); s += acc[e]; }
  float inv = 1.0f / s;
  #pragma unroll
  for (int e = 0; e < 8; ++e) gate[(size_t)e*NB + row] = acc[e] * inv;
}

// LN stats: lane holds partial sums for ITS row (c); reduce across the 4
// k-groups (lanes c, c+16, c+32, c+48), then fold coefficients.
__device__ __forceinline__ void ln_fold(float s, float q, float& sA, float& sB){
  s += __shfl_xor(s, 16, 64); q += __shfl_xor(q, 16, 64);
  s += __shfl_xor(s, 32, 64); q += __shfl_xor(q, 32, 64);
  float mu  = s * (1.0f/256.0f);
  float var = q * (1.0f/256.0f) - mu*mu;
  float rs  = rsqrtf(var + 1e-5f);
  sA = rs; sB = rs * mu;
}

// ---------------- mid layer (K=256, 256 cols), swapped operands ----------------
// A = weight frag (out_col = c), B = h frag (batch row = c). D per lane:
// batch row = c, out cols = 16ct + 4g + i  -> packed b64 epilogue store.
template<bool STATS>
__device__ __forceinline__ void mid_layer(
    const u16* __restrict__ w, const float* __restrict__ cse, const float* __restrict__ be,
    u16* hsh, u16* wbuf, int tid, int wrow, int g, int c,
    float sA, float sB, float& so, float& qo)
{
  Frag hB[8];
  #pragma unroll
  for (int kk = 0; kk < 8; ++kk)
    hB[kk].u = *(const uint4a*)&hsh[hidx(wrow + c, 32*kk + 8*g)];
  {
    uint4 st;
    stage_load16(w, tid, &st);
    stage_write16<9>(wbuf, tid, &st);
  }
  __syncthreads();
  #pragma unroll 1
  for (int ct = 0; ct < 16; ++ct){
    uint4 st;
    if (ct < 15) stage_load16(w + (ct+1)*16*256, tid, &st);   // issue early
    const u16* tb = wbuf + (ct&1)*4096;
    f32x4 a = {0,0,0,0};
    #pragma unroll
    for (int kk = 0; kk < 8; ++kk){
      Frag wf = read_wfrag<9>(tb, c, kk, g);
      a = MFMA16(wf.b, hB[kk].b, a);
    }
    float4 cs4 = *(const float4*)(cse + 16*ct + 4*g);
    float4 bi4 = *(const float4*)(be  + 16*ct + 4*g);
    const float* csp = (const float*)&cs4;
    const float* bip = (const float*)&bi4;
    Pack4 pk;
    #pragma unroll
    for (int i = 0; i < 4; ++i){
      float z = sA*a[i] - sB*csp[i] + bip[i];
      float v = mish_f(z);
      if (STATS){ so += v; qo += v*v; }
      pk.h[i] = (__bf16)v;
    }
    *(uint2a*)&hsh[hidx(wrow + c, 16*ct + 4*g)] = pk.u2;
    if (ct < 15) stage_write16<9>(wbuf + ((ct+1)&1)*4096, tid, &st);  // write late
    __syncthreads();
  }
}

// ---------------- main fused kernel ----------------
// 512 threads = 8 waves x 16 rows; LDS 80 KB -> 2 blocks/CU = 16 waves/CU
// (50% occupancy, 2x R7). Per-wave state halves -> fits 128-VGPR budget.
__global__ __launch_bounds__(512, 4)
void moe_main(const float* __restrict__ x, const float* __restrict__ gate,
              const u16* __restrict__ W1T, const u16* __restrict__ W2T,
              const u16* __restrict__ W3T, const u16* __restrict__ W4T,
              const float* __restrict__ b1, const float* __restrict__ b2,
              const float* __restrict__ b3, const float* __restrict__ b4,
              const float* __restrict__ cs2, const float* __restrict__ cs3,
              float* __restrict__ out)
{
  __shared__ u16 hsh[128*256];          // 64 KB
  __shared__ u16 wbuf[2*4096];          // 16 KB, two 8 KB tile slots
  const int t = threadIdx.x;
  const int lane = t & 63;
  const int wid  = t >> 6;              // 0..7
  const int g = lane >> 4;              // k-group / out-col quad
  const int c = lane & 15;              // batch row within wave
  const int wrow = wid * 16;
  const int rowblk = blockIdx.x * 128;
  const int myrow = rowblk + wrow + c;

  // x B-fragments: expert-invariant, load ONCE (f32 global -> bf16 regs)
  Frag xB[4];
  #pragma unroll
  for (int kk = 0; kk < 4; ++kk){
    const float* p = x + (size_t)myrow*128 + 32*kk + 8*g;
    float4 v0 = *(const float4*)p;
    float4 v1 = *(const float4*)(p + 4);
    Frag fr;
    fr.b[0] = (__bf16)v0.x; fr.b[1] = (__bf16)v0.y;
    fr.b[2] = (__bf16)v0.z; fr.b[3] = (__bf16)v0.w;
    fr.b[4] = (__bf16)v1.x; fr.b[5] = (__bf16)v1.y;
    fr.b[6] = (__bf16)v1.z; fr.b[7] = (__bf16)v1.w;
    xB[kk] = fr;
  }

  float oacc[8][4];
  #pragma unroll
  for (int ct = 0; ct < 8; ++ct)
    #pragma unroll
    for (int i = 0; i < 4; ++i) oacc[ct][i] = 0.f;

  #pragma unroll 1
  for (int e = 0; e < NEXP; ++e){
    const u16* w1 = W1T + e*(256*128);
    const u16* w2 = W2T + e*(256*256);
    const u16* w3 = W3T + e*(256*256);
    const u16* w4 = W4T + e*(128*256);
    const float* b1e = b1 + e*256;
    const float* b2e = b2 + e*256;
    const float* b3e = b3 + e*256;
    const float* b4e = b4 + e*128;
    const float* c2e = cs2 + e*256;
    const float* c3e = cs3 + e*256;

    // ---- Layer 1: [*,128]@[128,256], bias+mish, stats
    float s = 0.f, q = 0.f;
    {
      uint2 st;
      stage_load8(w1, t, &st);
      stage_write8<8>(wbuf, t, &st);
    }
    __syncthreads();
    #pragma unroll 1
    for (int ct = 0; ct < 16; ++ct){
      uint2 st;
      if (ct < 15) stage_load8(w1 + (ct+1)*16*128, t, &st);
      const u16* tb = wbuf + (ct&1)*4096;
      f32x4 a = {0,0,0,0};
      #pragma unroll
      for (int kk = 0; kk < 4; ++kk){
        Frag wf = read_wfrag<8>(tb, c, kk, g);
        a = MFMA16(wf.b, xB[kk].b, a);
      }
      float4 bi4 = *(const float4*)(b1e + 16*ct + 4*g);
      const float* bip = (const float*)&bi4;
      Pack4 pk;
      #pragma unroll
      for (int i = 0; i < 4; ++i){
        float z = a[i] + bip[i];
        float v = mish_f(z);
        s += v; q += v*v;
        pk.h[i] = (__bf16)v;
      }
      *(uint2a*)&hsh[hidx(wrow + c, 16*ct + 4*g)] = pk.u2;
      if (ct < 15) stage_write8<8>(wbuf + ((ct+1)&1)*4096, t, &st);
      __syncthreads();
    }
    float sA, sB;
    ln_fold(s, q, sA, sB);

    // ---- Layer 2 (LN folded) with stats
    s = 0.f; q = 0.f;
    mid_layer<true>(w2, c2e, b2e, hsh, wbuf, t, wrow, g, c, sA, sB, s, q);
    ln_fold(s, q, sA, sB);

    // ---- Layer 3 (LN folded), no stats
    mid_layer<false>(w3, c3e, b3e, hsh, wbuf, t, wrow, g, c, sA, sB, s, q);

    // ---- Layer 4: [*,256]@[256,128] + b4, gate-weighted accumulate
    {
      Frag hB[8];
      #pragma unroll
      for (int kk = 0; kk < 8; ++kk)
        hB[kk].u = *(const uint4a*)&hsh[hidx(wrow + c, 32*kk + 8*g)];
      float gv = gate[(size_t)e*NB + myrow];

      {
        uint4 st;
        stage_load16(w4, t, &st);
        stage_write16<9>(wbuf, t, &st);
      }
      __syncthreads();
      #pragma unroll
      for (int ct = 0; ct < 8; ++ct){
        uint4 st;
        if (ct < 7) stage_load16(w4 + (ct+1)*16*256, t, &st);
        const u16* tb = wbuf + (ct&1)*4096;
        f32x4 a = {0,0,0,0};
        #pragma unroll
        for (int kk = 0; kk < 8; ++kk){
          Frag wf = read_wfrag<9>(tb, c, kk, g);
          a = MFMA16(wf.b, hB[kk].b, a);
        }
        float4 bi4 = *(const float4*)(b4e + 16*ct + 4*g);
        const float* bip = (const float*)&bi4;
        #pragma unroll
        for (int i = 0; i < 4; ++i)
          oacc[ct][i] += gv * (a[i] + bip[i]);
        if (ct < 7) stage_write16<9>(wbuf + ((ct+1)&1)*4096, t, &st);
        __syncthreads();
      }
    }
  }

  // ---- store output [B,128] f32: lane writes 4 consecutive cols of its row
  #pragma unroll
  for (int ct = 0; ct < 8; ++ct){
    float4 o;
    o.x = oacc[ct][0]; o.y = oacc[ct][1]; o.z = oacc[ct][2]; o.w = oacc[ct][3];
    *(float4*)(out + (size_t)myrow*128 + 16*ct + 4*g) = o;
  }
}

extern "C" void kernel_launch(void* const* d_in, const int* in_sizes, int n_in,
                              void* d_out, int out_size, void* d_ws, size_t ws_size,
                              hipStream_t stream)
{
  const float* x  = (const float*)d_in[0];
  const float* Wg = (const float*)d_in[1];
  const float* bg = (const float*)d_in[2];
  const float* W1 = (const float*)d_in[3];
  const float* b1 = (const float*)d_in[4];
  const float* W2 = (const float*)d_in[5];
  const float* b2 = (const float*)d_in[6];
  const float* W3 = (const float*)d_in[7];
  const float* b3 = (const float*)d_in[8];
  const float* W4 = (const float*)d_in[9];
  const float* b4 = (const float*)d_in[10];
  float* out = (float*)d_out;

  char* ws = (char*)d_ws;
  size_t off = 0;
  float* gate = (float*)(ws + off); off += (size_t)NB * 8 * 4;        // 2 MB, [E][B]
  u16* W1T = (u16*)(ws + off); off += (size_t)8 * 256 * 128 * 2;      // 512 KB
  u16* W2T = (u16*)(ws + off); off += (size_t)8 * 256 * 256 * 2;      // 1 MB
  u16* W3T = (u16*)(ws + off); off += (size_t)8 * 256 * 256 * 2;      // 1 MB
  u16* W4T = (u16*)(ws + off); off += (size_t)8 * 128 * 256 * 2;      // 512 KB
  float* c2 = (float*)(ws + off); off += 8 * 256 * 4;                 // 8 KB
  float* c3 = (float*)(ws + off); off += 8 * 256 * 4;                 // 8 KB

  // weight prep: f32 [E][R][C] -> bf16 [E][C][R]
  transpose_cvt<<<8*(128/32)*(256/32), 256, 0, stream>>>(W1, W1T, 128, 256);
  transpose_cvt<<<8*(256/32)*(256/32), 256, 0, stream>>>(W2, W2T, 256, 256);
  transpose_cvt<<<8*(256/32)*(128/32), 256, 0, stream>>>(W4, W4T, 256, 128);
  transpose_cvt<<<8*(256/32)*(256/32), 256, 0, stream>>>(W3, W3T, 256, 256);
  csum_kernel<<<8, 256, 0, stream>>>(W2T, c2);
  csum_kernel<<<8, 256, 0, stream>>>(W3T, c3);
  gate_kernel<<<NB/256, 256, 0, stream>>>(x, Wg, bg, gate);

  moe_main<<<NB/128, 512, 0, stream>>>(x, gate, W1T, W2T, W3T, W4T,
                                       b1, b2, b3, b4, c2, c3, out);
}